// Round 18
// baseline (230.049 us; speedup 1.0000x reference)
//
#include <hip/hip_runtime.h>
#include <math.h>

// Sizes fixed by the problem.
#define BB 8
#define HH 256
#define WW 256
#define CC 64
// modes: kx in {0..31} u {224..255} (64 total), ky in {0..31}

__device__ inline void cmac(float2& a, float tx, float ty, float2 v) {
    a.x += tx * v.x - ty * v.y;
    a.y += tx * v.y + ty * v.x;
}
__device__ inline void fma4(float4& a, float s, float4 v) {
    a.x += s * v.x; a.y += s * v.y; a.z += s * v.z; a.w += s * v.w;
}

// ---------------------------------------------------------------------------
// K0: all twiddle tables (one kernel, 128 blocks x 256).
// Tf[x][j]  = e^{-2pi i kxa(j) x/256}                       (fwd x-DFT)
// Ti[j][x]  = (2/65536) e^{+2pi i kxa(j) x/256}             (inv x-DFT)
// Ty[y'][par*32+cs*16+m]: cs=0 -> cos(2pi ky y'/256), cs=1 -> -sin(...),
//                         ky = 2m+par                        (fwd y-DFT)
// T2[(pi*32+j)*128+p]: j=2m+ri; ri=0 -> cos(2pi ky p/256), ri=1 -> -sin(...),
//                         ky = 2m+pi                         (inv y-DFT)
// kxa(j) = j (j<32) else j+192.  parity(kxa(j)) == parity(j).
// ---------------------------------------------------------------------------
__global__ __launch_bounds__(256) void k_tw(float2* __restrict__ Tf,
                                            float2* __restrict__ Ti,
                                            float* __restrict__ Ty,
                                            float* __restrict__ T2) {
    int e = blockIdx.x * 256 + threadIdx.x;   // 0..32767
    if (e < 16384) {
        int x = e >> 6;
        int j = e & 63;
        int kxa = j + ((j >> 5) * 192);
        int tt = (kxa * x) & 255;
        float ang = (float)tt * (6.283185307179586f / 256.0f);
        float s, c;
        sincosf(ang, &s, &c);
        Tf[(size_t)x * 64 + j] = make_float2(c, -s);
        const float k = 2.0f / 65536.0f;
        Ti[(size_t)j * 256 + x] = make_float2(c * k, s * k);
    } else {
        int f = e - 16384;
        if (f < 8192) {
            int yp = f >> 6;
            int col = f & 63;
            int par = (col >> 5) & 1;
            int cs = (col >> 4) & 1;
            int m = col & 15;
            int ky = 2 * m + par;
            int tt = (ky * yp) & 255;
            float ang = (float)tt * (6.283185307179586f / 256.0f);
            float s, c;
            sincosf(ang, &s, &c);
            Ty[f] = cs ? -s : c;
        } else {
            int g = f - 8192;
            int pi = g >> 12;
            int j = (g >> 7) & 31;
            int p = g & 127;
            int m = j >> 1, ri = j & 1;
            int ky = 2 * m + pi;
            int tt = (ky * p) & 255;
            float ang = (float)tt * (6.283185307179586f / 256.0f);
            float s, c;
            sincosf(ang, &s, &c);
            T2[g] = ri ? -s : c;
        }
    }
}

// ---------------------------------------------------------------------------
// K1 (GEMM form v4 = v3 tile + LDS double-buffer, T14 async-stage pattern):
//   V[b][x][ky][i] = sum_{y'<128} Ty[y'][ky-col] * (u[y'] + (-1)^ky u[y'+128])[i]
// grid = 512: bx -> (b, x4); block = 256 thr = 4 waves, wave r owns row x4+r.
// ---------------------------------------------------------------------------
__global__ __launch_bounds__(256, 2) void k_fwd_y(const float* __restrict__ u,
                                                  const float* __restrict__ Ty,
                                                  float2* __restrict__ V) {
    __shared__ float ue[2][4][8 * 68];
    __shared__ float uo[2][4][8 * 68];
    __shared__ float Tt[2][8 * 68];

    int t = threadIdx.x;
    int bx = blockIdx.x;
    int b = bx >> 6;
    int x4 = (bx & 63) * 4;
    int r = t >> 6;            // wave = row
    int l = t & 63;
    int x = x4 + r;
    int i8 = (l & 7) * 8;
    int w = l >> 3;            // 0..7
    int p = w & 1;
    int kq = w >> 1;           // 0..3
    int yy = l >> 3;           // 0..7  (staging row, per-wave)
    int c0 = (l & 7) * 8;      // staging col (8 floats)
    int trow = t >> 5;         // 0..7  (Tt staging, block-wide)
    int tc = (t & 31) * 2;

    const float* ub = u + ((size_t)(b * HH + x)) * (WW * CC);

    float4 aR[4], aI[4], bR[4], bI[4];   // [m_idx]: i8+0..3 / i8+4..7
    #pragma unroll
    for (int m = 0; m < 4; ++m) {
        aR[m] = make_float4(0,0,0,0); aI[m] = make_float4(0,0,0,0);
        bR[m] = make_float4(0,0,0,0); bI[m] = make_float4(0,0,0,0);
    }

    float4 L0, L1, H0, H1;
    float2 TV;

    // prologue: stage tile 0
    {
        const float* plo = ub + (size_t)yy * CC + c0;
        const float* phi = plo + 128 * CC;
        L0 = *(const float4*)(plo);
        L1 = *(const float4*)(plo + 4);
        H0 = *(const float4*)(phi);
        H1 = *(const float4*)(phi + 4);
        TV = *(const float2*)(Ty + (size_t)trow * 64 + tc);
        int wb = yy * 68 + c0;
        float* uer = ue[0][r];
        float* uor = uo[0][r];
        *(float4*)(uer + wb)     = make_float4(L0.x+H0.x, L0.y+H0.y, L0.z+H0.z, L0.w+H0.w);
        *(float4*)(uer + wb + 4) = make_float4(L1.x+H1.x, L1.y+H1.y, L1.z+H1.z, L1.w+H1.w);
        *(float4*)(uor + wb)     = make_float4(L0.x-H0.x, L0.y-H0.y, L0.z-H0.z, L0.w-H0.w);
        *(float4*)(uor + wb + 4) = make_float4(L1.x-H1.x, L1.y-H1.y, L1.z-H1.z, L1.w-H1.w);
        *(float2*)(&Tt[0][trow * 68 + tc]) = TV;
    }
    __syncthreads();

    for (int yt = 0; yt < 16; ++yt) {
        int cur = yt & 1;
        if (yt < 15) {
            const float* plo = ub + (size_t)((yt + 1) * 8 + yy) * CC + c0;
            const float* phi = plo + 128 * CC;
            L0 = *(const float4*)(plo);
            L1 = *(const float4*)(plo + 4);
            H0 = *(const float4*)(phi);
            H1 = *(const float4*)(phi + 4);
            TV = *(const float2*)(Ty + (size_t)((yt + 1) * 8 + trow) * 64 + tc);
        }

        const float* uplane = p ? uo[cur][r] : ue[cur][r];
        const float* ttab = Tt[cur];
        #pragma unroll
        for (int y2 = 0; y2 < 8; ++y2) {
            const float* tb = ttab + y2 * 68 + p * 32 + kq * 2;
            float2 c01 = *(const float2*)(tb);        // cos m=2kq, 2kq+1
            float2 c89 = *(const float2*)(tb + 8);    // cos m=2kq+8, 2kq+9
            float2 s01 = *(const float2*)(tb + 16);   // -sin
            float2 s89 = *(const float2*)(tb + 24);
            const float* up = uplane + y2 * 68 + i8;
            float4 u0 = *(const float4*)(up);
            float4 u1 = *(const float4*)(up + 4);
            fma4(aR[0], c01.x, u0);  fma4(bR[0], c01.x, u1);
            fma4(aI[0], s01.x, u0);  fma4(bI[0], s01.x, u1);
            fma4(aR[1], c01.y, u0);  fma4(bR[1], c01.y, u1);
            fma4(aI[1], s01.y, u0);  fma4(bI[1], s01.y, u1);
            fma4(aR[2], c89.x, u0);  fma4(bR[2], c89.x, u1);
            fma4(aI[2], s89.x, u0);  fma4(bI[2], s89.x, u1);
            fma4(aR[3], c89.y, u0);  fma4(bR[3], c89.y, u1);
            fma4(aI[3], s89.y, u0);  fma4(bI[3], s89.y, u1);
        }

        if (yt < 15) {
            int nb = cur ^ 1;
            int wb = yy * 68 + c0;
            float* uer = ue[nb][r];
            float* uor = uo[nb][r];
            *(float4*)(uer + wb)     = make_float4(L0.x+H0.x, L0.y+H0.y, L0.z+H0.z, L0.w+H0.w);
            *(float4*)(uer + wb + 4) = make_float4(L1.x+H1.x, L1.y+H1.y, L1.z+H1.z, L1.w+H1.w);
            *(float4*)(uor + wb)     = make_float4(L0.x-H0.x, L0.y-H0.y, L0.z-H0.z, L0.w-H0.w);
            *(float4*)(uor + wb + 4) = make_float4(L1.x-H1.x, L1.y-H1.y, L1.z-H1.z, L1.w-H1.w);
            *(float2*)(&Tt[nb][trow * 68 + tc]) = TV;
        }
        __syncthreads();
    }

    // m_idx -> m: {2kq, 2kq+1, 2kq+8, 2kq+9}; ky = 2m+p
    int mv[4] = {2 * kq, 2 * kq + 1, 2 * kq + 8, 2 * kq + 9};
    #pragma unroll
    for (int mi = 0; mi < 4; ++mi) {
        int ky = 2 * mv[mi] + p;
        float2* vp = V + (size_t)(b * HH + x) * 2048 + ky * 64 + i8;
        *(float4*)(vp)     = make_float4(aR[mi].x, aI[mi].x, aR[mi].y, aI[mi].y);
        *(float4*)(vp + 2) = make_float4(aR[mi].z, aI[mi].z, aR[mi].w, aI[mi].w);
        *(float4*)(vp + 4) = make_float4(bR[mi].x, bI[mi].x, bR[mi].y, bI[mi].y);
        *(float4*)(vp + 6) = make_float4(bR[mi].z, bI[mi].z, bR[mi].w, bI[mi].w);
    }
}

// ---------------------------------------------------------------------------
// K2 (radix-2 GEMM v2, LDS double-buffer, 16-row tiles):
//   U[j][ky][b][i] = sum_{x<128} Tf[x][j] * (V[..x..] + (-1)^j V[..x+128..])
// grid = 1024: bx = jq*256 + (ky + 32*b). 8 tiles x 16 x-rows, ping-pong
// buffers (same 36 KB total LDS -> 4 blocks/CU). Staged regs = 18 floats.
// Per tile: issue loads(t+1) -> compute(buf cur) -> write buf^1 -> ONE barrier.
// ---------------------------------------------------------------------------
__global__ __launch_bounds__(256) void k_fwd_x(const float2* __restrict__ Tf,
                                               const float2* __restrict__ V,
                                               float2* __restrict__ U) {
    __shared__ float sRe[2][2 * 1024];   // [buf][par][xx*64+i] 8 KB each
    __shared__ float sIm[2][2 * 1024];
    __shared__ float2 Ts[2][16 * 16];    // [buf][xx][jj] 2 KB each

    int bx = blockIdx.x;
    int jq = bx >> 8;          // 0..3
    int ky = bx & 31;
    int b  = (bx >> 5) & 7;
    int t = threadIdx.x;
    int jr = t >> 5;      // 0..7
    int ir = t & 31;      // 0..31

    float2 a00 = {0,0}, a01 = {0,0}, a10 = {0,0}, a11 = {0,0};

    const float2* vb = V + (size_t)b * (HH * 2048) + ky * 64;
    int vrow = t >> 4;          // 0..15
    int vcol = (t & 15) * 4;    // complex index
    int tjj  = t & 15;          // Ts col (1 complex)
    int parOff = (jr & 1) * 1024;

    float4 l0, l1, h0, h1;
    float2 tv;

    // prologue: stage tile 0
    {
        const float2* plo = vb + (size_t)vrow * 2048 + vcol;
        const float2* phi = plo + 128 * 2048;
        l0 = *(const float4*)(plo);
        l1 = *(const float4*)(plo + 2);
        h0 = *(const float4*)(phi);
        h1 = *(const float4*)(phi + 2);
        tv = *(const float2*)((const float*)(Tf + (size_t)vrow * 64 + jq * 16 + tjj));
        int wb = vrow * 64 + vcol;
        *(float4*)(&sRe[0][wb])        = make_float4(l0.x+h0.x, l0.z+h0.z, l1.x+h1.x, l1.z+h1.z);
        *(float4*)(&sIm[0][wb])        = make_float4(l0.y+h0.y, l0.w+h0.w, l1.y+h1.y, l1.w+h1.w);
        *(float4*)(&sRe[0][1024 + wb]) = make_float4(l0.x-h0.x, l0.z-h0.z, l1.x-h1.x, l1.z-h1.z);
        *(float4*)(&sIm[0][1024 + wb]) = make_float4(l0.y-h0.y, l0.w-h0.w, l1.y-h1.y, l1.w-h1.w);
        Ts[0][vrow * 16 + tjj] = tv;
    }
    __syncthreads();

    for (int xt = 0; xt < 8; ++xt) {
        int cur = xt & 1;
        if (xt < 7) {
            const float2* plo = vb + (size_t)((xt + 1) * 16 + vrow) * 2048 + vcol;
            const float2* phi = plo + 128 * 2048;
            l0 = *(const float4*)(plo);
            l1 = *(const float4*)(plo + 2);
            h0 = *(const float4*)(phi);
            h1 = *(const float4*)(phi + 2);
            tv = *(const float2*)((const float*)(Tf + (size_t)((xt + 1) * 16 + vrow) * 64 + jq * 16 + tjj));
        }

        const float2* tss = Ts[cur];
        const float* reb = &sRe[cur][parOff];
        const float* imb = &sIm[cur][parOff];
        #pragma unroll
        for (int xx = 0; xx < 16; ++xx) {
            float2 t0 = tss[xx * 16 + jr];
            float2 t1 = tss[xx * 16 + jr + 8];
            const float* re = reb + xx * 64;
            const float* im = imb + xx * 64;
            float vr0 = re[ir], vr1 = re[ir + 32];
            float vi0 = im[ir], vi1 = im[ir + 32];
            a00.x += t0.x*vr0 - t0.y*vi0;  a00.y += t0.x*vi0 + t0.y*vr0;
            a01.x += t0.x*vr1 - t0.y*vi1;  a01.y += t0.x*vi1 + t0.y*vr1;
            a10.x += t1.x*vr0 - t1.y*vi0;  a10.y += t1.x*vi0 + t1.y*vr0;
            a11.x += t1.x*vr1 - t1.y*vi1;  a11.y += t1.x*vi1 + t1.y*vr1;
        }

        if (xt < 7) {
            int nb = cur ^ 1;
            int wb = vrow * 64 + vcol;
            *(float4*)(&sRe[nb][wb])        = make_float4(l0.x+h0.x, l0.z+h0.z, l1.x+h1.x, l1.z+h1.z);
            *(float4*)(&sIm[nb][wb])        = make_float4(l0.y+h0.y, l0.w+h0.w, l1.y+h1.y, l1.w+h1.w);
            *(float4*)(&sRe[nb][1024 + wb]) = make_float4(l0.x-h0.x, l0.z-h0.z, l1.x-h1.x, l1.z-h1.z);
            *(float4*)(&sIm[nb][1024 + wb]) = make_float4(l0.y-h0.y, l0.w-h0.w, l1.y-h1.y, l1.w-h1.w);
            Ts[nb][vrow * 16 + tjj] = tv;
        }
        __syncthreads();
    }

    int j0 = jq * 16 + jr;
    float2* u0 = U + ((size_t)(j0 * 32 + ky) * 8 + b) * 64 + ir;
    u0[0]  = a00;
    u0[32] = a01;
    float2* u1 = U + ((size_t)((j0 + 8) * 32 + ky) * 8 + b) * 64 + ir;
    u1[0]  = a10;
    u1[32] = a11;
}

// ---------------------------------------------------------------------------
// K3 (fused weight-transpose + mode mul, wS ping-pong double-buffer):
// OF[b][ky][j][o] = sum_i U[j][ky][b][i] * (wr[i,o,kxl,ky], wi[i,o,kxl,ky])
// grid = 1024: bx = j + 64*kyt + 512*oh.
// ---------------------------------------------------------------------------
__global__ __launch_bounds__(256) void k_modew(const float* __restrict__ wpr,
                                               const float* __restrict__ wpi,
                                               const float* __restrict__ wnr,
                                               const float* __restrict__ wni,
                                               const float2* __restrict__ U,
                                               float2* __restrict__ OF) {
    __shared__ float2 uS[4 * 8 * 64];      // [kyr][b][i]     16 KB
    __shared__ float2 wS[2][4 * 8 * 32];   // [buf][kyr][ir][o32] 16 KB

    int bx = blockIdx.x;
    int j   = bx & 63;
    int kyt = (bx >> 6) & 7;
    int oh  = bx >> 9;
    int ky0 = kyt * 4;
    int sel = j >> 5, kxl = j & 31;
    const float* sr = sel ? wnr : wpr;
    const float* si = sel ? wni : wpi;
    int tid = threadIdx.x;

    int o32 = tid & 31;
    int bh  = tid >> 5;
    int irS = tid >> 5;
    int ooS = tid & 31;

    // stage U slice (2048 float2 = 1024 float4, coalesced 16 B/lane)
    {
        const float4* up4 = (const float4*)(U + (size_t)(j * 32 + ky0) * 512);
        float4* uS4 = (float4*)uS;
        #pragma unroll
        for (int k = 0; k < 4; ++k) uS4[tid + 256 * k] = up4[tid + 256 * k];
    }
    // prologue: stage w tile 0
    float4 r0, q0;
    {
        size_t base = (((size_t)(irS * 64 + oh * 32 + ooS)) * 32 + kxl) * 32 + ky0;
        r0 = *(const float4*)(sr + base);
        q0 = *(const float4*)(si + base);
        float2* wrow = wS[0] + irS * 32 + ooS;
        wrow[0 * 256] = make_float2(r0.x, q0.x);
        wrow[1 * 256] = make_float2(r0.y, q0.y);
        wrow[2 * 256] = make_float2(r0.z, q0.z);
        wrow[3 * 256] = make_float2(r0.w, q0.w);
    }
    __syncthreads();

    float2 acc[4];
    #pragma unroll
    for (int k = 0; k < 4; ++k) acc[k] = make_float2(0.f, 0.f);

    for (int it = 0; it < 8; ++it) {
        int cur = it & 1;
        if (it < 7) {
            int ig = (it + 1) * 8 + irS;
            size_t base = (((size_t)(ig * 64 + oh * 32 + ooS)) * 32 + kxl) * 32 + ky0;
            r0 = *(const float4*)(sr + base);
            q0 = *(const float4*)(si + base);
        }

        const float2* wcur = wS[cur];
        #pragma unroll
        for (int ir = 0; ir < 8; ++ir) {
            int ig = it * 8 + ir;
            #pragma unroll
            for (int ky = 0; ky < 4; ++ky) {
                float2 wv = wcur[ky * 256 + ir * 32 + o32];
                float2 uv = uS[ky * 512 + bh * 64 + ig];
                acc[ky].x += uv.x * wv.x - uv.y * wv.y;
                acc[ky].y += uv.x * wv.y + uv.y * wv.x;
            }
        }

        if (it < 7) {
            float2* wrow = wS[cur ^ 1] + irS * 32 + ooS;
            wrow[0 * 256] = make_float2(r0.x, q0.x);
            wrow[1 * 256] = make_float2(r0.y, q0.y);
            wrow[2 * 256] = make_float2(r0.z, q0.z);
            wrow[3 * 256] = make_float2(r0.w, q0.w);
        }
        __syncthreads();
    }

    int og = oh * 32 + o32;
    #pragma unroll
    for (int ky = 0; ky < 4; ++ky) {
        OF[((size_t)(bh * 32 + ky0 + ky) * 64 + j) * 64 + og] = acc[ky];
    }
}

// ---------------------------------------------------------------------------
// K4 (radix-2 GEMM v2, LDS double-buffer, 16-j tiles): for x<128:
//   Se = sum_{even j} Ti[j][x] OF[b][ky][j][o], So = sum_{odd j} ...
//   A[b][x]     = (Se+So)*sc,  A[b][x+128] = (Se-So)*sc   (sc: ky==0 -> 0.5)
// grid = 1024: bx = xt*256 + (ky + 32*b). 4 tiles x 16 j, ping-pong buffers
// (24 KB total LDS, unchanged). Staged regs = 12 floats.
// ---------------------------------------------------------------------------
__global__ __launch_bounds__(256) void k_inv_x(const float2* __restrict__ Ti,
                                               const float2* __restrict__ OF,
                                               float2* __restrict__ A) {
    __shared__ float2 Ts[2][16 * 32];   // [buf][jj][xp]  4 KB each
    __shared__ float2 Os[2][16 * 64];   // [buf][jj][o]   8 KB each

    int bx = blockIdx.x;
    int xt = bx >> 8;          // 0..3
    int ky = bx & 31;
    int b  = (bx >> 5) & 7;
    int t = threadIdx.x;
    int or_ = t & 15;
    int xr = t >> 4;     // 0..15

    float2 acc[2][2][4];   // [parity][p][q]
    #pragma unroll
    for (int pa = 0; pa < 2; ++pa)
        #pragma unroll
        for (int p = 0; p < 2; ++p)
            #pragma unroll
            for (int q = 0; q < 4; ++q) acc[pa][p][q] = make_float2(0.f, 0.f);

    const float2* ofb = OF + (size_t)(b * 32 + ky) * 4096;
    int sj = t >> 4;         // 0..15
    int sx = (t & 15) * 2;   // Ts cols (2 complex)
    int so = (t & 15) * 4;   // Os cols (4 complex)

    float4 t0, o0, o1;

    // prologue: stage tile 0
    {
        t0 = *(const float4*)(Ti + (size_t)sj * 256 + xt * 32 + sx);
        const float2* osrc = ofb + (size_t)sj * 64 + so;
        o0 = *(const float4*)(osrc);
        o1 = *(const float4*)(osrc + 2);
        *(float4*)&Ts[0][sj * 32 + sx] = t0;
        float2* od = &Os[0][sj * 64 + so];
        *(float4*)(od)     = o0;
        *(float4*)(od + 2) = o1;
    }
    __syncthreads();

    for (int kt = 0; kt < 4; ++kt) {
        int cur = kt & 1;
        if (kt < 3) {
            t0 = *(const float4*)(Ti + (size_t)((kt + 1) * 16 + sj) * 256 + xt * 32 + sx);
            const float2* osrc = ofb + (size_t)((kt + 1) * 16 + sj) * 64 + so;
            o0 = *(const float4*)(osrc);
            o1 = *(const float4*)(osrc + 2);
        }

        const float2* tsb = Ts[cur];
        const float2* osb = Os[cur];
        #pragma unroll
        for (int jj = 0; jj < 16; ++jj) {
            float4 tp = *(const float4*)&tsb[jj * 32 + xr * 2];
            float2 q0 = osb[jj * 64 + or_];
            float2 q1 = osb[jj * 64 + or_ + 16];
            float2 q2 = osb[jj * 64 + or_ + 32];
            float2 q3 = osb[jj * 64 + or_ + 48];
            const int pa = jj & 1;     // constant after unroll
            cmac(acc[pa][0][0], tp.x, tp.y, q0);
            cmac(acc[pa][0][1], tp.x, tp.y, q1);
            cmac(acc[pa][0][2], tp.x, tp.y, q2);
            cmac(acc[pa][0][3], tp.x, tp.y, q3);
            cmac(acc[pa][1][0], tp.z, tp.w, q0);
            cmac(acc[pa][1][1], tp.z, tp.w, q1);
            cmac(acc[pa][1][2], tp.z, tp.w, q2);
            cmac(acc[pa][1][3], tp.z, tp.w, q3);
        }

        if (kt < 3) {
            int nb = cur ^ 1;
            *(float4*)&Ts[nb][sj * 32 + sx] = t0;
            float2* od = &Os[nb][sj * 64 + so];
            *(float4*)(od)     = o0;
            *(float4*)(od + 2) = o1;
        }
        __syncthreads();
    }

    float sc = (ky == 0) ? 0.5f : 1.0f;
    #pragma unroll
    for (int p = 0; p < 2; ++p) {
        int x = xt * 32 + xr * 2 + p;
        float2* alo = A + ((size_t)(b * 256 + x) * 32 + ky) * 64 + or_;
        float2* ahi = A + ((size_t)(b * 256 + x + 128) * 32 + ky) * 64 + or_;
        #pragma unroll
        for (int q = 0; q < 4; ++q) {
            float2 se = acc[0][p][q], so2 = acc[1][p][q];
            alo[16 * q] = make_float2((se.x + so2.x) * sc, (se.y + so2.y) * sc);
            ahi[16 * q] = make_float2((se.x - so2.x) * sc, (se.y - so2.y) * sc);
        }
    }
}

// ---------------------------------------------------------------------------
// K5 (GEMM form v4 — best measured variant): per (b,x):
//   S_pi[p][o] = sum_j T2[pi][j][p] * A'[pi][j][o]   (K=32 per parity)
//   out[p][o] = S_0+S_1 ; out[p+128][o] = S_0-S_1    (p in [0,128))
// grid = B*H, 256 threads: pr = t>>4 (p = pr*8+pp), o4 = (t&15)*4.
// acc[2][8] = 64 floats (~100 VGPR, no spill). LDS 51 KB -> 3 blocks/CU.
// ---------------------------------------------------------------------------
__global__ __launch_bounds__(256) void k_inv_y(const float* __restrict__ T2g,
                                               const float2* __restrict__ A,
                                               float* __restrict__ out) {
    __shared__ float As[64 * 68];     // [pi*32 + j][o]+pad   17.4 KB
    __shared__ float T2s[64 * 132];   // [pi*32 + j][p]+pad   33.8 KB

    int t = threadIdx.x;
    int b = blockIdx.x >> 8;
    int x = blockIdx.x & 255;

    // stage A' planar: A[b][x][ky][o] -> As[(ky&1)*32 + 2*(ky>>1)+{re,im}][o]
    {
        int ky = t >> 3;            // 0..31
        int oc = (t & 7) * 8;       // complex col
        const float2* ap = A + (size_t)(b * 256 + x) * 2048 + ky * 64 + oc;
        float4 g0 = *(const float4*)(ap);
        float4 g1 = *(const float4*)(ap + 2);
        float4 g2 = *(const float4*)(ap + 4);
        float4 g3 = *(const float4*)(ap + 6);
        int pi = ky & 1, m = ky >> 1;
        float* re = As + ((pi * 32) + 2 * m) * 68 + oc;
        float* im = As + ((pi * 32) + 2 * m + 1) * 68 + oc;
        *(float4*)(re)     = make_float4(g0.x, g0.z, g1.x, g1.z);
        *(float4*)(re + 4) = make_float4(g2.x, g2.z, g3.x, g3.z);
        *(float4*)(im)     = make_float4(g0.y, g0.w, g1.y, g1.w);
        *(float4*)(im + 4) = make_float4(g2.y, g2.w, g3.y, g3.w);
    }
    // stage full T2: 8192 floats / 256 threads = 32 = 8 float4
    {
        int row = t >> 2;           // 0..63
        int c = (t & 3) * 32;       // 0..96
        const float* tg = T2g + (size_t)row * 128 + c;
        float* td = T2s + row * 132 + c;
        #pragma unroll
        for (int k = 0; k < 8; ++k) {
            float4 q = *(const float4*)(tg + 4 * k);
            *(float4*)(td + 4 * k) = q;
        }
    }
    __syncthreads();

    int pr = t >> 4;            // 0..15 -> p = pr*8 + pp
    int o4 = (t & 15) * 4;

    float4 acc[2][8];           // [pi][pp] over 4 o's
    #pragma unroll
    for (int pi = 0; pi < 2; ++pi)
        #pragma unroll
        for (int pp = 0; pp < 8; ++pp) acc[pi][pp] = make_float4(0,0,0,0);

    #pragma unroll
    for (int pi = 0; pi < 2; ++pi) {
        #pragma unroll
        for (int jj = 0; jj < 32; ++jj) {
            const float* trow = T2s + (pi * 32 + jj) * 132 + pr * 8;
            float4 ta = *(const float4*)(trow);
            float4 tb = *(const float4*)(trow + 4);
            float4 av = *(const float4*)(As + (pi * 32 + jj) * 68 + o4);
            fma4(acc[pi][0], ta.x, av);
            fma4(acc[pi][1], ta.y, av);
            fma4(acc[pi][2], ta.z, av);
            fma4(acc[pi][3], ta.w, av);
            fma4(acc[pi][4], tb.x, av);
            fma4(acc[pi][5], tb.y, av);
            fma4(acc[pi][6], tb.z, av);
            fma4(acc[pi][7], tb.w, av);
        }
    }

    float* op = out + (size_t)(b * 256 + x) * (256 * 64);
    #pragma unroll
    for (int pp = 0; pp < 8; ++pp) {
        int p = pr * 8 + pp;
        float4 e = acc[0][pp], d = acc[1][pp];
        *(float4*)(op + (size_t)p * 64 + o4)
            = make_float4(e.x+d.x, e.y+d.y, e.z+d.z, e.w+d.w);
        *(float4*)(op + (size_t)(p + 128) * 64 + o4)
            = make_float4(e.x-d.x, e.y-d.y, e.z-d.z, e.w-d.w);
    }
}

// ---------------------------------------------------------------------------
extern "C" void kernel_launch(void* const* d_in, const int* in_sizes, int n_in,
                              void* d_out, int out_size, void* d_ws, size_t ws_size,
                              hipStream_t stream) {
    const float* u   = (const float*)d_in[0];
    const float* wpr = (const float*)d_in[1];
    const float* wpi = (const float*)d_in[2];
    const float* wnr = (const float*)d_in[3];
    const float* wni = (const float*)d_in[4];
    float* out = (float*)d_out;

    char* ws = (char*)d_ws;
    // U : 64*32*8*64  float2 =  8 MiB  @ 0
    // OF:  8*32*64*64 float2 =  8 MiB  @ 8 MiB
    // V : 8*256*32*64 float2 = 32 MiB  @ 16 MiB (A aliases V)
    // Tf: 128 KiB @ 48 MiB; Ti: 128 KiB; Ty: 32 KiB; T2: 32 KiB
    float2* U  = (float2*)(ws);
    float2* OF = (float2*)(ws + 8388608);
    float2* V  = (float2*)(ws + 16777216);
    float2* A  = V;
    float2* Tf = (float2*)(ws + 50331648);
    float2* Ti = (float2*)(ws + 50331648 + 131072);
    float*  Ty = (float*)(ws + 50331648 + 262144);
    float*  T2 = (float*)(ws + 50331648 + 262144 + 32768);

    k_tw<<<128, 256, 0, stream>>>(Tf, Ti, Ty, T2);
    k_fwd_y<<<512, 256, 0, stream>>>(u, Ty, V);
    k_fwd_x<<<1024, 256, 0, stream>>>(Tf, V, U);
    k_modew<<<1024, 256, 0, stream>>>(wpr, wpi, wnr, wni, U, OF);
    k_inv_x<<<1024, 256, 0, stream>>>(Ti, OF, A);
    k_inv_y<<<BB * HH, 256, 0, stream>>>(T2, A, out);
}

// Round 19
// 214.477 us; speedup vs baseline: 1.0726x; 1.0726x over previous
//
#include <hip/hip_runtime.h>
#include <math.h>

// Sizes fixed by the problem.
#define BB 8
#define HH 256
#define WW 256
#define CC 64
// modes: kx in {0..31} u {224..255} (64 total), ky in {0..31}

__device__ inline void cmac(float2& a, float tx, float ty, float2 v) {
    a.x += tx * v.x - ty * v.y;
    a.y += tx * v.y + ty * v.x;
}
__device__ inline void fma4(float4& a, float s, float4 v) {
    a.x += s * v.x; a.y += s * v.y; a.z += s * v.z; a.w += s * v.w;
}

// ---------------------------------------------------------------------------
// K0: all twiddle tables (one kernel, 128 blocks x 256).
// Tf[x][j]  = e^{-2pi i kxa(j) x/256}                       (fwd x-DFT)
// Ti[j][x]  = (2/65536) e^{+2pi i kxa(j) x/256}             (inv x-DFT)
// Ty[y'][par*32+cs*16+m]: cs=0 -> cos(2pi ky y'/256), cs=1 -> -sin(...),
//                         ky = 2m+par                        (fwd y-DFT)
// T2[(pi*32+j)*128+p]: j=2m+ri; ri=0 -> cos(2pi ky p/256), ri=1 -> -sin(...),
//                         ky = 2m+pi                         (inv y-DFT)
// kxa(j) = j (j<32) else j+192.  parity(kxa(j)) == parity(j).
// ---------------------------------------------------------------------------
__global__ __launch_bounds__(256) void k_tw(float2* __restrict__ Tf,
                                            float2* __restrict__ Ti,
                                            float* __restrict__ Ty,
                                            float* __restrict__ T2) {
    int e = blockIdx.x * 256 + threadIdx.x;   // 0..32767
    if (e < 16384) {
        int x = e >> 6;
        int j = e & 63;
        int kxa = j + ((j >> 5) * 192);
        int tt = (kxa * x) & 255;
        float ang = (float)tt * (6.283185307179586f / 256.0f);
        float s, c;
        sincosf(ang, &s, &c);
        Tf[(size_t)x * 64 + j] = make_float2(c, -s);
        const float k = 2.0f / 65536.0f;
        Ti[(size_t)j * 256 + x] = make_float2(c * k, s * k);
    } else {
        int f = e - 16384;
        if (f < 8192) {
            int yp = f >> 6;
            int col = f & 63;
            int par = (col >> 5) & 1;
            int cs = (col >> 4) & 1;
            int m = col & 15;
            int ky = 2 * m + par;
            int tt = (ky * yp) & 255;
            float ang = (float)tt * (6.283185307179586f / 256.0f);
            float s, c;
            sincosf(ang, &s, &c);
            Ty[f] = cs ? -s : c;
        } else {
            int g = f - 8192;
            int pi = g >> 12;
            int j = (g >> 7) & 31;
            int p = g & 127;
            int m = j >> 1, ri = j & 1;
            int ky = 2 * m + pi;
            int tt = (ky * p) & 255;
            float ang = (float)tt * (6.283185307179586f / 256.0f);
            float s, c;
            sincosf(ang, &s, &c);
            T2[g] = ri ? -s : c;
        }
    }
}

// ---------------------------------------------------------------------------
// K1 (GEMM form v4 = v3 tile + LDS double-buffer, T14 async-stage pattern):
//   V[b][x][ky][i] = sum_{y'<128} Ty[y'][ky-col] * (u[y'] + (-1)^ky u[y'+128])[i]
// grid = 512: bx -> (b, x4); block = 256 thr = 4 waves, wave r owns row x4+r.
// ---------------------------------------------------------------------------
__global__ __launch_bounds__(256, 2) void k_fwd_y(const float* __restrict__ u,
                                                  const float* __restrict__ Ty,
                                                  float2* __restrict__ V) {
    __shared__ float ue[2][4][8 * 68];
    __shared__ float uo[2][4][8 * 68];
    __shared__ float Tt[2][8 * 68];

    int t = threadIdx.x;
    int bx = blockIdx.x;
    int b = bx >> 6;
    int x4 = (bx & 63) * 4;
    int r = t >> 6;            // wave = row
    int l = t & 63;
    int x = x4 + r;
    int i8 = (l & 7) * 8;
    int w = l >> 3;            // 0..7
    int p = w & 1;
    int kq = w >> 1;           // 0..3
    int yy = l >> 3;           // 0..7  (staging row, per-wave)
    int c0 = (l & 7) * 8;      // staging col (8 floats)
    int trow = t >> 5;         // 0..7  (Tt staging, block-wide)
    int tc = (t & 31) * 2;

    const float* ub = u + ((size_t)(b * HH + x)) * (WW * CC);

    float4 aR[4], aI[4], bR[4], bI[4];   // [m_idx]: i8+0..3 / i8+4..7
    #pragma unroll
    for (int m = 0; m < 4; ++m) {
        aR[m] = make_float4(0,0,0,0); aI[m] = make_float4(0,0,0,0);
        bR[m] = make_float4(0,0,0,0); bI[m] = make_float4(0,0,0,0);
    }

    float4 L0, L1, H0, H1;
    float2 TV;

    // prologue: stage tile 0
    {
        const float* plo = ub + (size_t)yy * CC + c0;
        const float* phi = plo + 128 * CC;
        L0 = *(const float4*)(plo);
        L1 = *(const float4*)(plo + 4);
        H0 = *(const float4*)(phi);
        H1 = *(const float4*)(phi + 4);
        TV = *(const float2*)(Ty + (size_t)trow * 64 + tc);
        int wb = yy * 68 + c0;
        float* uer = ue[0][r];
        float* uor = uo[0][r];
        *(float4*)(uer + wb)     = make_float4(L0.x+H0.x, L0.y+H0.y, L0.z+H0.z, L0.w+H0.w);
        *(float4*)(uer + wb + 4) = make_float4(L1.x+H1.x, L1.y+H1.y, L1.z+H1.z, L1.w+H1.w);
        *(float4*)(uor + wb)     = make_float4(L0.x-H0.x, L0.y-H0.y, L0.z-H0.z, L0.w-H0.w);
        *(float4*)(uor + wb + 4) = make_float4(L1.x-H1.x, L1.y-H1.y, L1.z-H1.z, L1.w-H1.w);
        *(float2*)(&Tt[0][trow * 68 + tc]) = TV;
    }
    __syncthreads();

    for (int yt = 0; yt < 16; ++yt) {
        int cur = yt & 1;
        if (yt < 15) {
            const float* plo = ub + (size_t)((yt + 1) * 8 + yy) * CC + c0;
            const float* phi = plo + 128 * CC;
            L0 = *(const float4*)(plo);
            L1 = *(const float4*)(plo + 4);
            H0 = *(const float4*)(phi);
            H1 = *(const float4*)(phi + 4);
            TV = *(const float2*)(Ty + (size_t)((yt + 1) * 8 + trow) * 64 + tc);
        }

        const float* uplane = p ? uo[cur][r] : ue[cur][r];
        const float* ttab = Tt[cur];
        #pragma unroll
        for (int y2 = 0; y2 < 8; ++y2) {
            const float* tb = ttab + y2 * 68 + p * 32 + kq * 2;
            float2 c01 = *(const float2*)(tb);        // cos m=2kq, 2kq+1
            float2 c89 = *(const float2*)(tb + 8);    // cos m=2kq+8, 2kq+9
            float2 s01 = *(const float2*)(tb + 16);   // -sin
            float2 s89 = *(const float2*)(tb + 24);
            const float* up = uplane + y2 * 68 + i8;
            float4 u0 = *(const float4*)(up);
            float4 u1 = *(const float4*)(up + 4);
            fma4(aR[0], c01.x, u0);  fma4(bR[0], c01.x, u1);
            fma4(aI[0], s01.x, u0);  fma4(bI[0], s01.x, u1);
            fma4(aR[1], c01.y, u0);  fma4(bR[1], c01.y, u1);
            fma4(aI[1], s01.y, u0);  fma4(bI[1], s01.y, u1);
            fma4(aR[2], c89.x, u0);  fma4(bR[2], c89.x, u1);
            fma4(aI[2], s89.x, u0);  fma4(bI[2], s89.x, u1);
            fma4(aR[3], c89.y, u0);  fma4(bR[3], c89.y, u1);
            fma4(aI[3], s89.y, u0);  fma4(bI[3], s89.y, u1);
        }

        if (yt < 15) {
            int nb = cur ^ 1;
            int wb = yy * 68 + c0;
            float* uer = ue[nb][r];
            float* uor = uo[nb][r];
            *(float4*)(uer + wb)     = make_float4(L0.x+H0.x, L0.y+H0.y, L0.z+H0.z, L0.w+H0.w);
            *(float4*)(uer + wb + 4) = make_float4(L1.x+H1.x, L1.y+H1.y, L1.z+H1.z, L1.w+H1.w);
            *(float4*)(uor + wb)     = make_float4(L0.x-H0.x, L0.y-H0.y, L0.z-H0.z, L0.w-H0.w);
            *(float4*)(uor + wb + 4) = make_float4(L1.x-H1.x, L1.y-H1.y, L1.z-H1.z, L1.w-H1.w);
            *(float2*)(&Tt[nb][trow * 68 + tc]) = TV;
        }
        __syncthreads();
    }

    // m_idx -> m: {2kq, 2kq+1, 2kq+8, 2kq+9}; ky = 2m+p
    int mv[4] = {2 * kq, 2 * kq + 1, 2 * kq + 8, 2 * kq + 9};
    #pragma unroll
    for (int mi = 0; mi < 4; ++mi) {
        int ky = 2 * mv[mi] + p;
        float2* vp = V + (size_t)(b * HH + x) * 2048 + ky * 64 + i8;
        *(float4*)(vp)     = make_float4(aR[mi].x, aI[mi].x, aR[mi].y, aI[mi].y);
        *(float4*)(vp + 2) = make_float4(aR[mi].z, aI[mi].z, aR[mi].w, aI[mi].w);
        *(float4*)(vp + 4) = make_float4(bR[mi].x, bI[mi].x, bR[mi].y, bI[mi].y);
        *(float4*)(vp + 6) = make_float4(bR[mi].z, bI[mi].z, bR[mi].w, bI[mi].w);
    }
}

// ---------------------------------------------------------------------------
// K2 (radix-2 GEMM, R17 single-buffer version — R18's 16-row dbuf regressed:
// compute/barrier halved below the latency-hiding threshold):
//   U[j][ky][b][i] = sum_{x<128} Tf[x][j] * (V[..x..] + (-1)^j V[..x+128..])
// grid = 1024: bx = jq*256 + (ky + 32*b).
// ---------------------------------------------------------------------------
__global__ __launch_bounds__(256) void k_fwd_x(const float2* __restrict__ Tf,
                                               const float2* __restrict__ V,
                                               float2* __restrict__ U) {
    __shared__ float sRe[2 * 2048];   // [par][xx*64+i] 16 KB
    __shared__ float sIm[2 * 2048];   // 16 KB
    __shared__ float2 Ts[32 * 16];    // [xx][jj] 4 KB

    int bx = blockIdx.x;
    int jq = bx >> 8;          // 0..3
    int ky = bx & 31;
    int b  = (bx >> 5) & 7;
    int t = threadIdx.x;
    int jr = t >> 5;      // 0..7
    int ir = t & 31;      // 0..31

    float2 a00 = {0,0}, a01 = {0,0}, a10 = {0,0}, a11 = {0,0};

    const float2* vb = V + (size_t)b * (HH * 2048) + ky * 64;
    int vrow = t >> 3;          // 0..31
    int vcol = (t & 7) * 8;     // complex index
    int tjj = (t & 7) * 2;      // 0..14
    int parOff = (jr & 1) * 2048;

    for (int x0 = 0; x0 < 128; x0 += 32) {
        const float2* plo = vb + (size_t)(x0 + vrow) * 2048 + vcol;
        const float2* phi = plo + 128 * 2048;
        float4 l0 = *(const float4*)(plo);
        float4 l1 = *(const float4*)(plo + 2);
        float4 l2 = *(const float4*)(plo + 4);
        float4 l3 = *(const float4*)(plo + 6);
        float4 h0 = *(const float4*)(phi);
        float4 h1 = *(const float4*)(phi + 2);
        float4 h2 = *(const float4*)(phi + 4);
        float4 h3 = *(const float4*)(phi + 6);
        float4 tv = *(const float4*)(Tf + (size_t)(x0 + vrow) * 64 + jq * 16 + tjj);

        __syncthreads();   // previous tile's LDS reads complete
        *(float4*)&Ts[vrow * 16 + tjj] = tv;
        int wb = vrow * 64 + vcol;
        *(float4*)(sRe + wb)            = make_float4(l0.x+h0.x, l0.z+h0.z, l1.x+h1.x, l1.z+h1.z);
        *(float4*)(sRe + wb + 4)        = make_float4(l2.x+h2.x, l2.z+h2.z, l3.x+h3.x, l3.z+h3.z);
        *(float4*)(sIm + wb)            = make_float4(l0.y+h0.y, l0.w+h0.w, l1.y+h1.y, l1.w+h1.w);
        *(float4*)(sIm + wb + 4)        = make_float4(l2.y+h2.y, l2.w+h2.w, l3.y+h3.y, l3.w+h3.w);
        *(float4*)(sRe + 2048 + wb)     = make_float4(l0.x-h0.x, l0.z-h0.z, l1.x-h1.x, l1.z-h1.z);
        *(float4*)(sRe + 2048 + wb + 4) = make_float4(l2.x-h2.x, l2.z-h2.z, l3.x-h3.x, l3.z-h3.z);
        *(float4*)(sIm + 2048 + wb)     = make_float4(l0.y-h0.y, l0.w-h0.w, l1.y-h1.y, l1.w-h1.w);
        *(float4*)(sIm + 2048 + wb + 4) = make_float4(l2.y-h2.y, l2.w-h2.w, l3.y-h3.y, l3.w-h3.w);
        __syncthreads();

        #pragma unroll
        for (int xx = 0; xx < 32; ++xx) {
            float2 t0 = Ts[xx * 16 + jr];
            float2 t1 = Ts[xx * 16 + jr + 8];
            const float* re = sRe + parOff + xx * 64;
            const float* im = sIm + parOff + xx * 64;
            float vr0 = re[ir], vr1 = re[ir + 32];
            float vi0 = im[ir], vi1 = im[ir + 32];
            a00.x += t0.x*vr0 - t0.y*vi0;  a00.y += t0.x*vi0 + t0.y*vr0;
            a01.x += t0.x*vr1 - t0.y*vi1;  a01.y += t0.x*vi1 + t0.y*vr1;
            a10.x += t1.x*vr0 - t1.y*vi0;  a10.y += t1.x*vi0 + t1.y*vr0;
            a11.x += t1.x*vr1 - t1.y*vi1;  a11.y += t1.x*vi1 + t1.y*vr1;
        }
    }

    int j0 = jq * 16 + jr;
    float2* u0 = U + ((size_t)(j0 * 32 + ky) * 8 + b) * 64 + ir;
    u0[0]  = a00;
    u0[32] = a01;
    float2* u1 = U + ((size_t)((j0 + 8) * 32 + ky) * 8 + b) * 64 + ir;
    u1[0]  = a10;
    u1[32] = a11;
}

// ---------------------------------------------------------------------------
// K3 (fused weight-transpose + mode mul, wS ping-pong double-buffer):
// OF[b][ky][j][o] = sum_i U[j][ky][b][i] * (wr[i,o,kxl,ky], wi[i,o,kxl,ky])
// grid = 1024: bx = j + 64*kyt + 512*oh.
// ---------------------------------------------------------------------------
__global__ __launch_bounds__(256) void k_modew(const float* __restrict__ wpr,
                                               const float* __restrict__ wpi,
                                               const float* __restrict__ wnr,
                                               const float* __restrict__ wni,
                                               const float2* __restrict__ U,
                                               float2* __restrict__ OF) {
    __shared__ float2 uS[4 * 8 * 64];      // [kyr][b][i]     16 KB
    __shared__ float2 wS[2][4 * 8 * 32];   // [buf][kyr][ir][o32] 16 KB

    int bx = blockIdx.x;
    int j   = bx & 63;
    int kyt = (bx >> 6) & 7;
    int oh  = bx >> 9;
    int ky0 = kyt * 4;
    int sel = j >> 5, kxl = j & 31;
    const float* sr = sel ? wnr : wpr;
    const float* si = sel ? wni : wpi;
    int tid = threadIdx.x;

    int o32 = tid & 31;
    int bh  = tid >> 5;
    int irS = tid >> 5;
    int ooS = tid & 31;

    // stage U slice (2048 float2 = 1024 float4, coalesced 16 B/lane)
    {
        const float4* up4 = (const float4*)(U + (size_t)(j * 32 + ky0) * 512);
        float4* uS4 = (float4*)uS;
        #pragma unroll
        for (int k = 0; k < 4; ++k) uS4[tid + 256 * k] = up4[tid + 256 * k];
    }
    // prologue: stage w tile 0
    float4 r0, q0;
    {
        size_t base = (((size_t)(irS * 64 + oh * 32 + ooS)) * 32 + kxl) * 32 + ky0;
        r0 = *(const float4*)(sr + base);
        q0 = *(const float4*)(si + base);
        float2* wrow = wS[0] + irS * 32 + ooS;
        wrow[0 * 256] = make_float2(r0.x, q0.x);
        wrow[1 * 256] = make_float2(r0.y, q0.y);
        wrow[2 * 256] = make_float2(r0.z, q0.z);
        wrow[3 * 256] = make_float2(r0.w, q0.w);
    }
    __syncthreads();

    float2 acc[4];
    #pragma unroll
    for (int k = 0; k < 4; ++k) acc[k] = make_float2(0.f, 0.f);

    for (int it = 0; it < 8; ++it) {
        int cur = it & 1;
        if (it < 7) {
            int ig = (it + 1) * 8 + irS;
            size_t base = (((size_t)(ig * 64 + oh * 32 + ooS)) * 32 + kxl) * 32 + ky0;
            r0 = *(const float4*)(sr + base);
            q0 = *(const float4*)(si + base);
        }

        const float2* wcur = wS[cur];
        #pragma unroll
        for (int ir = 0; ir < 8; ++ir) {
            int ig = it * 8 + ir;
            #pragma unroll
            for (int ky = 0; ky < 4; ++ky) {
                float2 wv = wcur[ky * 256 + ir * 32 + o32];
                float2 uv = uS[ky * 512 + bh * 64 + ig];
                acc[ky].x += uv.x * wv.x - uv.y * wv.y;
                acc[ky].y += uv.x * wv.y + uv.y * wv.x;
            }
        }

        if (it < 7) {
            float2* wrow = wS[cur ^ 1] + irS * 32 + ooS;
            wrow[0 * 256] = make_float2(r0.x, q0.x);
            wrow[1 * 256] = make_float2(r0.y, q0.y);
            wrow[2 * 256] = make_float2(r0.z, q0.z);
            wrow[3 * 256] = make_float2(r0.w, q0.w);
        }
        __syncthreads();
    }

    int og = oh * 32 + o32;
    #pragma unroll
    for (int ky = 0; ky < 4; ++ky) {
        OF[((size_t)(bh * 32 + ky0 + ky) * 64 + j) * 64 + og] = acc[ky];
    }
}

// ---------------------------------------------------------------------------
// K4 (radix-2 GEMM, R17 single-buffer version — R18's 16-j dbuf regressed):
//   Se = sum_{even j} Ti[j][x] OF[b][ky][j][o], So = sum_{odd j} ...
//   A[b][x]     = (Se+So)*sc,  A[b][x+128] = (Se-So)*sc   (sc: ky==0 -> 0.5)
// grid = 1024: bx = xt*256 + (ky + 32*b).
// ---------------------------------------------------------------------------
__global__ __launch_bounds__(256) void k_inv_x(const float2* __restrict__ Ti,
                                               const float2* __restrict__ OF,
                                               float2* __restrict__ A) {
    __shared__ float2 Ts[32 * 32];   // [jj][xp]  8 KB
    __shared__ float2 Os[32 * 64];   // [jj][o]  16 KB

    int bx = blockIdx.x;
    int xt = bx >> 8;          // 0..3
    int ky = bx & 31;
    int b  = (bx >> 5) & 7;
    int t = threadIdx.x;
    int or_ = t & 15;
    int xr = t >> 4;     // 0..15

    float2 acc[2][2][4];   // [parity][p][q]
    #pragma unroll
    for (int pa = 0; pa < 2; ++pa)
        #pragma unroll
        for (int p = 0; p < 2; ++p)
            #pragma unroll
            for (int q = 0; q < 4; ++q) acc[pa][p][q] = make_float2(0.f, 0.f);

    const float2* ofb = OF + (size_t)(b * 32 + ky) * 4096;
    int sj = t >> 3;         // 0..31
    int sx = (t & 7) * 4;    // Ts cols (4 complex)
    int so = (t & 7) * 8;    // Os cols (8 complex)

    for (int kh = 0; kh < 2; ++kh) {
        const float2* tsrc = Ti + (size_t)(kh * 32 + sj) * 256 + xt * 32 + sx;
        float4 t0 = *(const float4*)(tsrc);
        float4 t1 = *(const float4*)(tsrc + 2);
        const float2* osrc = ofb + (size_t)(kh * 32 + sj) * 64 + so;
        float4 o0 = *(const float4*)(osrc);
        float4 o1 = *(const float4*)(osrc + 2);
        float4 o2 = *(const float4*)(osrc + 4);
        float4 o3 = *(const float4*)(osrc + 6);

        __syncthreads();
        *(float4*)&Ts[sj * 32 + sx]     = t0;
        *(float4*)&Ts[sj * 32 + sx + 2] = t1;
        float2* od = &Os[sj * 64 + so];
        *(float4*)(od)     = o0;
        *(float4*)(od + 2) = o1;
        *(float4*)(od + 4) = o2;
        *(float4*)(od + 6) = o3;
        __syncthreads();

        #pragma unroll
        for (int jj = 0; jj < 32; ++jj) {
            float4 tp = *(const float4*)&Ts[jj * 32 + xr * 2];
            float2 q0 = Os[jj * 64 + or_];
            float2 q1 = Os[jj * 64 + or_ + 16];
            float2 q2 = Os[jj * 64 + or_ + 32];
            float2 q3 = Os[jj * 64 + or_ + 48];
            const int pa = jj & 1;     // constant after unroll
            cmac(acc[pa][0][0], tp.x, tp.y, q0);
            cmac(acc[pa][0][1], tp.x, tp.y, q1);
            cmac(acc[pa][0][2], tp.x, tp.y, q2);
            cmac(acc[pa][0][3], tp.x, tp.y, q3);
            cmac(acc[pa][1][0], tp.z, tp.w, q0);
            cmac(acc[pa][1][1], tp.z, tp.w, q1);
            cmac(acc[pa][1][2], tp.z, tp.w, q2);
            cmac(acc[pa][1][3], tp.z, tp.w, q3);
        }
    }

    float sc = (ky == 0) ? 0.5f : 1.0f;
    #pragma unroll
    for (int p = 0; p < 2; ++p) {
        int x = xt * 32 + xr * 2 + p;
        float2* alo = A + ((size_t)(b * 256 + x) * 32 + ky) * 64 + or_;
        float2* ahi = A + ((size_t)(b * 256 + x + 128) * 32 + ky) * 64 + or_;
        #pragma unroll
        for (int q = 0; q < 4; ++q) {
            float2 se = acc[0][p][q], so2 = acc[1][p][q];
            alo[16 * q] = make_float2((se.x + so2.x) * sc, (se.y + so2.y) * sc);
            ahi[16 * q] = make_float2((se.x - so2.x) * sc, (se.y - so2.y) * sc);
        }
    }
}

// ---------------------------------------------------------------------------
// K5 (GEMM form v4 — best measured variant): per (b,x):
//   S_pi[p][o] = sum_j T2[pi][j][p] * A'[pi][j][o]   (K=32 per parity)
//   out[p][o] = S_0+S_1 ; out[p+128][o] = S_0-S_1    (p in [0,128))
// grid = B*H, 256 threads: pr = t>>4 (p = pr*8+pp), o4 = (t&15)*4.
// acc[2][8] = 64 floats (~100 VGPR, no spill). LDS 51 KB -> 3 blocks/CU.
// ---------------------------------------------------------------------------
__global__ __launch_bounds__(256) void k_inv_y(const float* __restrict__ T2g,
                                               const float2* __restrict__ A,
                                               float* __restrict__ out) {
    __shared__ float As[64 * 68];     // [pi*32 + j][o]+pad   17.4 KB
    __shared__ float T2s[64 * 132];   // [pi*32 + j][p]+pad   33.8 KB

    int t = threadIdx.x;
    int b = blockIdx.x >> 8;
    int x = blockIdx.x & 255;

    // stage A' planar: A[b][x][ky][o] -> As[(ky&1)*32 + 2*(ky>>1)+{re,im}][o]
    {
        int ky = t >> 3;            // 0..31
        int oc = (t & 7) * 8;       // complex col
        const float2* ap = A + (size_t)(b * 256 + x) * 2048 + ky * 64 + oc;
        float4 g0 = *(const float4*)(ap);
        float4 g1 = *(const float4*)(ap + 2);
        float4 g2 = *(const float4*)(ap + 4);
        float4 g3 = *(const float4*)(ap + 6);
        int pi = ky & 1, m = ky >> 1;
        float* re = As + ((pi * 32) + 2 * m) * 68 + oc;
        float* im = As + ((pi * 32) + 2 * m + 1) * 68 + oc;
        *(float4*)(re)     = make_float4(g0.x, g0.z, g1.x, g1.z);
        *(float4*)(re + 4) = make_float4(g2.x, g2.z, g3.x, g3.z);
        *(float4*)(im)     = make_float4(g0.y, g0.w, g1.y, g1.w);
        *(float4*)(im + 4) = make_float4(g2.y, g2.w, g3.y, g3.w);
    }
    // stage full T2: 8192 floats / 256 threads = 32 = 8 float4
    {
        int row = t >> 2;           // 0..63
        int c = (t & 3) * 32;       // 0..96
        const float* tg = T2g + (size_t)row * 128 + c;
        float* td = T2s + row * 132 + c;
        #pragma unroll
        for (int k = 0; k < 8; ++k) {
            float4 q = *(const float4*)(tg + 4 * k);
            *(float4*)(td + 4 * k) = q;
        }
    }
    __syncthreads();

    int pr = t >> 4;            // 0..15 -> p = pr*8 + pp
    int o4 = (t & 15) * 4;

    float4 acc[2][8];           // [pi][pp] over 4 o's
    #pragma unroll
    for (int pi = 0; pi < 2; ++pi)
        #pragma unroll
        for (int pp = 0; pp < 8; ++pp) acc[pi][pp] = make_float4(0,0,0,0);

    #pragma unroll
    for (int pi = 0; pi < 2; ++pi) {
        #pragma unroll
        for (int jj = 0; jj < 32; ++jj) {
            const float* trow = T2s + (pi * 32 + jj) * 132 + pr * 8;
            float4 ta = *(const float4*)(trow);
            float4 tb = *(const float4*)(trow + 4);
            float4 av = *(const float4*)(As + (pi * 32 + jj) * 68 + o4);
            fma4(acc[pi][0], ta.x, av);
            fma4(acc[pi][1], ta.y, av);
            fma4(acc[pi][2], ta.z, av);
            fma4(acc[pi][3], ta.w, av);
            fma4(acc[pi][4], tb.x, av);
            fma4(acc[pi][5], tb.y, av);
            fma4(acc[pi][6], tb.z, av);
            fma4(acc[pi][7], tb.w, av);
        }
    }

    float* op = out + (size_t)(b * 256 + x) * (256 * 64);
    #pragma unroll
    for (int pp = 0; pp < 8; ++pp) {
        int p = pr * 8 + pp;
        float4 e = acc[0][pp], d = acc[1][pp];
        *(float4*)(op + (size_t)p * 64 + o4)
            = make_float4(e.x+d.x, e.y+d.y, e.z+d.z, e.w+d.w);
        *(float4*)(op + (size_t)(p + 128) * 64 + o4)
            = make_float4(e.x-d.x, e.y-d.y, e.z-d.z, e.w-d.w);
    }
}

// ---------------------------------------------------------------------------
extern "C" void kernel_launch(void* const* d_in, const int* in_sizes, int n_in,
                              void* d_out, int out_size, void* d_ws, size_t ws_size,
                              hipStream_t stream) {
    const float* u   = (const float*)d_in[0];
    const float* wpr = (const float*)d_in[1];
    const float* wpi = (const float*)d_in[2];
    const float* wnr = (const float*)d_in[3];
    const float* wni = (const float*)d_in[4];
    float* out = (float*)d_out;

    char* ws = (char*)d_ws;
    // U : 64*32*8*64  float2 =  8 MiB  @ 0
    // OF:  8*32*64*64 float2 =  8 MiB  @ 8 MiB
    // V : 8*256*32*64 float2 = 32 MiB  @ 16 MiB (A aliases V)
    // Tf: 128 KiB @ 48 MiB; Ti: 128 KiB; Ty: 32 KiB; T2: 32 KiB
    float2* U  = (float2*)(ws);
    float2* OF = (float2*)(ws + 8388608);
    float2* V  = (float2*)(ws + 16777216);
    float2* A  = V;
    float2* Tf = (float2*)(ws + 50331648);
    float2* Ti = (float2*)(ws + 50331648 + 131072);
    float*  Ty = (float*)(ws + 50331648 + 262144);
    float*  T2 = (float*)(ws + 50331648 + 262144 + 32768);

    k_tw<<<128, 256, 0, stream>>>(Tf, Ti, Ty, T2);
    k_fwd_y<<<512, 256, 0, stream>>>(u, Ty, V);
    k_fwd_x<<<1024, 256, 0, stream>>>(Tf, V, U);
    k_modew<<<1024, 256, 0, stream>>>(wpr, wpi, wnr, wni, U, OF);
    k_inv_x<<<1024, 256, 0, stream>>>(Ti, OF, A);
    k_inv_y<<<BB * HH, 256, 0, stream>>>(T2, A, out);
}